// Round 1
// baseline (267.244 us; speedup 1.0000x reference)
//
#include <hip/hip_runtime.h>

// Problem shape (fixed by setup_inputs):
//   tens:    (B=8, C=32, H=128, W=128) f32
//   filters: (S=16, 1, 7, 7)           f32
//   shifts:  (16, 2) int32 in [0,8)
//   out:     (B, C*S, H, W) = (8, 512, 128, 128) f32  -> 67,108,864 elems
//
// Analysis (see journal): the non-cyclic roll-mask keeps only wrapped rows
// i < sy (value from row 134+i-sy of the bottom/right-zero-padded plane).
// Rows 128..133 are padding, so the shifted plane has at most ONE nonzero
// element: (0,0) = tens[n,127,127], and only when shifts[s]==(7,7).
// The VALID 7x7 correlation then leaves a single possibly-nonzero output
// per (n,s) plane at (0,0): tens[n,127,127] * filters[s,0,0,0].
//
// => kernel = vectorized zero-fill of 256 MB + corner patch, fused.

#define HW    16384      // 128*128 plane elements
#define HW4   4096       // plane size in float4
#define CS    512        // C*S output channels
#define C_    32
#define S_    16

__global__ __launch_bounds__(256) void shifted_conv_fill(
    const float* __restrict__ tens,
    const float* __restrict__ filters,
    const int*   __restrict__ shifts,
    float*       __restrict__ out,
    long long n4)
{
    long long v = (long long)blockIdx.x * blockDim.x + threadIdx.x;
    const long long stride = (long long)gridDim.x * blockDim.x;

    for (; v < n4; v += stride) {
        float4 val = make_float4(0.f, 0.f, 0.f, 0.f);
        // First float4 of each (b,ch) plane holds the only possibly-nonzero
        // element (oh=0, ow=0).
        if ((v & (HW4 - 1)) == 0) {
            long long plane = v >> 12;           // v / HW4
            int ch = (int)(plane & (CS - 1));    // plane % 512
            int b  = (int)(plane >> 9);          // plane / 512
            int c  = ch >> 4;                    // ch / 16
            int s  = ch & (S_ - 1);              // ch % 16
            int sy = shifts[2 * s];
            int sx = shifts[2 * s + 1];
            if (sy == 7 && sx == 7) {
                int n = b * C_ + c;
                val.x = tens[(long long)n * HW + (HW - 1)] * filters[s * 49];
            }
        }
        reinterpret_cast<float4*>(out)[v] = val;
    }
}

extern "C" void kernel_launch(void* const* d_in, const int* in_sizes, int n_in,
                              void* d_out, int out_size, void* d_ws, size_t ws_size,
                              hipStream_t stream) {
    const float* tens    = (const float*)d_in[0];
    const float* filters = (const float*)d_in[1];
    const int*   shifts  = (const int*)d_in[2];
    float*       out     = (float*)d_out;

    const long long n4 = (long long)out_size / 4;   // 16,777,216 float4 stores

    // 8192 blocks x 256 threads -> 2M threads, 8 float4 (128 B) per thread,
    // grid-stride keeps consecutive lanes on consecutive 16B segments.
    dim3 grid(8192), block(256);
    shifted_conv_fill<<<grid, block, 0, stream>>>(tens, filters, shifts, out, n4);
}

// Round 2
// 266.045 us; speedup vs baseline: 1.0045x; 1.0045x over previous
//
#include <hip/hip_runtime.h>

// Problem shape (fixed by setup_inputs):
//   tens:    (B=8, C=32, H=128, W=128) f32
//   filters: (S=16, 1, 7, 7)           f32
//   shifts:  (16, 2) int32 in [0,8)
//   out:     (B, C*S, H, W) = (8, 512, 128, 128) f32  -> 67,108,864 elems
//
// Analysis (verified R1, absmax=0): the non-cyclic roll-mask keeps only
// wrapped rows i < sy, sourced from rows 134+i-sy of the bottom/right-
// zero-padded plane. Rows/cols 128..133 are padding, so the shifted plane
// has at most ONE nonzero element: (0,0) = tens[n,127,127], and only when
// shifts[s]==(7,7). The VALID 7x7 correlation then leaves a single
// possibly-nonzero output per (n,s) plane:
//   out[b, c*16+s, 0, 0] = tens[b,c,127,127] * filters[s,0,0,0]
// All other 67M outputs are exactly zero.
//
// R2 strategy: zero-fill via hipMemsetAsync (rocclr fillBufferAligned,
// measured 6.4 TB/s on this chip) + a 4096-thread corner-patch kernel.

#define HW    16384      // 128*128 plane elements
#define CS    512        // C*S output channels
#define C_    32
#define S_    16

__global__ __launch_bounds__(256) void corner_patch(
    const float* __restrict__ tens,
    const float* __restrict__ filters,
    const int*   __restrict__ shifts,
    float*       __restrict__ out)
{
    int plane = blockIdx.x * blockDim.x + threadIdx.x;   // 0 .. 4095
    int ch = plane & (CS - 1);     // plane % 512
    int b  = plane >> 9;           // plane / 512
    int c  = ch >> 4;              // ch / 16
    int s  = ch & (S_ - 1);        // ch % 16
    int sy = shifts[2 * s];
    int sx = shifts[2 * s + 1];
    if (sy == 7 && sx == 7) {
        int n = b * C_ + c;
        out[(long long)plane * HW] =
            tens[(long long)n * HW + (HW - 1)] * filters[s * 49];
    }
}

extern "C" void kernel_launch(void* const* d_in, const int* in_sizes, int n_in,
                              void* d_out, int out_size, void* d_ws, size_t ws_size,
                              hipStream_t stream) {
    const float* tens    = (const float*)d_in[0];
    const float* filters = (const float*)d_in[1];
    const int*   shifts  = (const int*)d_in[2];
    float*       out     = (float*)d_out;

    // 256 MB zero-fill on the proven 6.4 TB/s fillBuffer path.
    hipMemsetAsync(out, 0, (size_t)out_size * sizeof(float), stream);

    // Patch the <=4096 possibly-nonzero corner elements (one thread/plane).
    corner_patch<<<dim3(16), dim3(256), 0, stream>>>(tens, filters, shifts, out);
}